// Round 1
// 393.145 us; speedup vs baseline: 1.0104x; 1.0104x over previous
//
#include <hip/hip_runtime.h>
#include <math.h>

#define BB 64
#define TT 4096
#define CC 64

constexpr int L0v = 2048, U0v = 3069, V0v = 1535, P0v = 2048;
constexpr int L1v = 1024, U1v = 1533, V1v = 767,  P1v = 1024;
constexpr int OUTL = 6144;
constexpr long NTOT = (long)BB * TT * CC;
#define VT 63        // pool outputs per block (128 conv outputs)
#define JROWS 88
#define X1STR 68     // floats per row (64 data + 4 pad -> 4-bank step per row)
#define X0STR 72     // shorts per row (bf16 stream)
#define CBSTR 130

// ---- transpose x[b][t][c] -> xtr[b][c][t], fused global sum/sumsq ----
__global__ __launch_bounds__(256) void transpose_stats(const float* __restrict__ x,
                                                       float* __restrict__ xtr,
                                                       double* __restrict__ part) {
  __shared__ float tile[64][65];
  __shared__ double sd1[256], sd2[256];
  const int tt = blockIdx.x;
  const int b = blockIdx.y;
  const int t0 = tt * 64;
  const long xbase = (long)b * TT * CC + (long)t0 * CC;
  const int tid = threadIdx.x;
  double a = 0, q = 0;
  {
    int c = tid & 63;
    for (int r = tid >> 6; r < 64; r += 4) {
      float v = x[xbase + r * 64 + c];
      tile[r][c] = v;
      a += v; q += (double)v * (double)v;
    }
  }
  sd1[tid] = a; sd2[tid] = q;
  __syncthreads();
  {
    int tl = tid & 63;
    for (int cc = tid >> 6; cc < 64; cc += 4)
      xtr[((long)(b * 64 + cc)) * TT + t0 + tl] = tile[tl][cc];
  }
  for (int s = 128; s > 0; s >>= 1) {
    if (tid < s) { sd1[tid] += sd1[tid + s]; sd2[tid] += sd2[tid + s]; }
    __syncthreads();
  }
  if (tid == 0) {
    part[(b * 64 + tt) * 2] = sd1[0];
    part[(b * 64 + tt) * 2 + 1] = sd2[0];
  }
}

// ---------------- closed-form index helpers ----------------
__device__ __host__ inline int pad_idx(int p, int brk, int dup, int sub) {
  if (p < brk) { int q = p / 3; int r = p - 3 * q; return 2 * q + (r == 2 ? 1 : 0); }
  if (p < brk + 2) return dup;
  return p - sub;
}

__device__ inline int fmap_code(int k) {
  if (k == 0) return 2048 + 0;
  if (k == 1) return 0;
  if (k < 5462) {
    int m = k - 2;
    int c = m / 12;
    int j = m - 12 * c;
    if (j <= 3)  return 2048 + (1 + 9 * c + j);
    if (j == 4)  return 1 + 3 * c;
    if (j <= 8)  return 2048 + (9 * c + j);
    if (j == 9)  return 2 + 3 * c;
    if (j == 10) return 2048 + (9 + 9 * c);
    return 3 + 3 * c;
  }
  return k - 4096;
}

// ---- merged prep: block 0 = stats_final, 1..64 = weight_norm, 65..88 = codes ----
__global__ __launch_bounds__(256) void prep(const double* __restrict__ part,
                                            double* __restrict__ stats,
                                            const float* __restrict__ v,
                                            const float* __restrict__ g,
                                            float* __restrict__ wt,
                                            int* __restrict__ codes) {
  const int blk = blockIdx.x;
  const int tid = threadIdx.x;
  if (blk == 0) {
    __shared__ double s1[256], s2[256];
    double a = 0, q = 0;
    for (int i = tid; i < 4096; i += 256) { a += part[2 * i]; q += part[2 * i + 1]; }
    s1[tid] = a; s2[tid] = q;
    __syncthreads();
    for (int s = 128; s > 0; s >>= 1) {
      if (tid < s) { s1[tid] += s1[tid + s]; s2[tid] += s2[tid + s]; }
      __syncthreads();
    }
    if (tid == 0) {
      double n = (double)NTOT;
      double mean = s1[0] / n;
      double var = (s2[0] - s1[0] * s1[0] / n) / (n - 1.0);
      stats[0] = mean; stats[1] = sqrt(var);
      stats[2] = 0.8 / mean;
      stats[3] = 0.8 / sqrt(var);
    }
  } else if (blk <= 64) {
    int o = blk - 1;
    __shared__ float red[256];
    __shared__ float scale;
    float vv = (tid < 192) ? v[o * 192 + tid] : 0.f;
    red[tid] = vv * vv;
    __syncthreads();
    for (int s = 128; s > 0; s >>= 1) {
      if (tid < s) red[tid] += red[tid + s];
      __syncthreads();
    }
    if (tid == 0) scale = g[o] / sqrtf(red[0]);
    __syncthreads();
    if (tid < 192) {
      int i = tid / 3, k = tid - 3 * i;
      wt[(k * 64 + i) * 64 + o] = scale * vv;
    }
  } else {
    int k = (blk - 65) * 256 + tid;
    if (k < OUTL) {
      int s = fmap_code(k);
      int type, xi, yi = 0;
      if (s < 2048) {
        if ((s & 1) == 0) { type = 0; xi = 2 * s; }
        else { int p = s >> 1; yi = pad_idx(p, 768, 512, 257); xi = 4 * p + 3; type = 2; }
      } else {
        int p = s - 2048;
        if ((p & 1) == 0) { type = 0; xi = p; }
        else { int q = p >> 1; yi = pad_idx(q, 1536, 1024, 513); xi = 2 * q + 1; type = 1; }
      }
      codes[k] = type | (xi << 2) | (yi << 14);
    }
  }
}

// ---- bf16 round-to-nearest-even-ish (round-half-away tie fix via lsb) ----
__device__ inline unsigned bf16rn(float f) {
  unsigned u = __float_as_uint(f);
  return (u + 0x7fffu + ((u >> 16) & 1u)) >> 16;
}

// ---- fused conv (stride2, dil3) + bias + maxpool(3,s2,p1) + elu + gauss ----
// LDS holds only the two raw streams: X1 (fp32) + X0 (bf16).  The three J
// phases are linear combos j = alpha_r*x1 + beta_r*x0 formed at read time
// (alpha = {inv_mean, 0, inv_std}, beta = {0.2, 1, 0.2}).  LDS 72KB -> 36.6KB
// => 4 blocks/CU (was 2): the kernel was latency-bound (VALUBusy 41%,
// occupancy 19%), not FMA-bound.  x0-in-bf16 is safe: x0 enters with coeff
// 0.2 under a ~2600x-scaled x1 term (phases 0/2) or as an O(1)-output conv
// (phase 1); added error ~1e-3 << current absmax.
__global__ __launch_bounds__(256, 4) void conv_pool(
    const float* __restrict__ x, const float* __restrict__ wt,
    const float* __restrict__ cbias, const double* __restrict__ stats,
    float* __restrict__ y1, int L, int U, int V, int mult, int off1) {
  const int b = blockIdx.x;
  const int v0 = blockIdx.y * VT;
  const int tid = threadIdx.x;
  const int lane = tid & 63;
  const int og = __builtin_amdgcn_readfirstlane((tid >> 6) * 16);

  const int u0 = 2 * v0 - 1;
  const int uv_lo = max(u0, 0);
  const int uv_hi = min(u0 + 127, U - 1);
  const int t_lo = (2 * uv_lo) / 3;
  int t_hi = (2 * uv_hi + 6) / 3;
  if (t_hi > L - 1) t_hi = L - 1;
  const int rows = t_hi - t_lo + 1;     // <= 88

  // X1: 88*68*4 = 23936 B ; X0: 88*72*2 = 12672 B ; total 36608 B
  // epilogue cbf[64][130]*4 = 33280 B reuses the same region
  __shared__ __align__(16) unsigned char smem8[JROWS * X1STR * 4 + JROWS * X0STR * 2];
  float* X1 = (float*)smem8;
  unsigned short* X0 = (unsigned short*)(smem8 + JROWS * X1STR * 4);
  float* cbf = (float*)smem8;

  const float inv_mean = (float)stats[2];
  const float inv_std  = (float)stats[3];
  const long xbase = (long)b * TT * CC;

  // stage the two raw streams
  for (int idx = tid; idx < rows * 16; idx += 256) {
    int tr = idx >> 4, c4 = (idx & 15) * 4;
    int t = t_lo + tr;
    float4 x0 = *(const float4*)&x[xbase + (long)(mult * t) * CC + c4];
    float4 x1 = *(const float4*)&x[xbase + (long)(mult * t + off1) * CC + c4];
    *(float4*)&X1[tr * X1STR + c4] = x1;
    uint2 p;
    p.x = bf16rn(x0.x) | (bf16rn(x0.y) << 16);
    p.y = bf16rn(x0.z) | (bf16rn(x0.w) << 16);
    *(uint2*)&X0[tr * X0STR + c4] = p;   // c4*2 bytes offset: 8B aligned
  }
  __syncthreads();

  const int uA = u0 + lane, uB = uA + 64;
  const int ucA = min(max(uA, 0), U - 1);
  const int ucB = min(uB, U - 1);
  const int t0A = (2 * ucA) / 3, t0B = (2 * ucB) / 3;
  const int rA = 2 * ucA - 3 * t0A, rB = 2 * ucB - 3 * t0B;

  const float aA = (rA == 0) ? inv_mean : ((rA == 2) ? inv_std : 0.f);
  const float bA = (rA == 1) ? 1.f : 0.2f;
  const float aB = (rB == 0) ? inv_mean : ((rB == 2) ? inv_std : 0.f);
  const float bB = (rB == 1) ? 1.f : 0.2f;

  const float* X1A = X1 + (t0A - t_lo) * X1STR;
  const float* X1B = X1 + (t0B - t_lo) * X1STR;
  const unsigned short* X0A = X0 + (t0A - t_lo) * X0STR;
  const unsigned short* X0B = X0 + (t0B - t_lo) * X0STR;

  float accA[16], accB[16];
  {
    const float* cb_s = cbias + og;
#pragma unroll
    for (int o = 0; o < 16; o++) { accA[o] = cb_s[o]; accB[o] = cb_s[o]; }
  }

  for (int k = 0; k < 3; k++) {
    const float4* r1a = (const float4*)(X1A + k * X1STR);
    const float4* r1b = (const float4*)(X1B + k * X1STR);
    const uint2* r0a = (const uint2*)(X0A + k * X0STR);
    const uint2* r0b = (const uint2*)(X0B + k * X0STR);
    const float* wk = wt + k * 4096 + og;
#pragma unroll 4
    for (int i4 = 0; i4 < 16; i4++) {
      float4 x1A = r1a[i4];
      float4 x1B = r1b[i4];
      uint2 qA = r0a[i4];
      uint2 qB = r0b[i4];
      float4 jA, jB;
      jA.x = fmaf(aA, x1A.x, bA * __uint_as_float(qA.x << 16));
      jA.y = fmaf(aA, x1A.y, bA * __uint_as_float(qA.x & 0xffff0000u));
      jA.z = fmaf(aA, x1A.z, bA * __uint_as_float(qA.y << 16));
      jA.w = fmaf(aA, x1A.w, bA * __uint_as_float(qA.y & 0xffff0000u));
      jB.x = fmaf(aB, x1B.x, bB * __uint_as_float(qB.x << 16));
      jB.y = fmaf(aB, x1B.y, bB * __uint_as_float(qB.x & 0xffff0000u));
      jB.z = fmaf(aB, x1B.z, bB * __uint_as_float(qB.y << 16));
      jB.w = fmaf(aB, x1B.w, bB * __uint_as_float(qB.y & 0xffff0000u));
      const float* wp = wk + i4 * 256;
#pragma unroll
      for (int o = 0; o < 16; o++) {
        float w0 = wp[o], w1 = wp[64 + o], w2 = wp[128 + o], w3 = wp[192 + o];
        accA[o] = fmaf(jA.x, w0, accA[o]);
        accA[o] = fmaf(jA.y, w1, accA[o]);
        accA[o] = fmaf(jA.z, w2, accA[o]);
        accA[o] = fmaf(jA.w, w3, accA[o]);
        accB[o] = fmaf(jB.x, w0, accB[o]);
        accB[o] = fmaf(jB.y, w1, accB[o]);
        accB[o] = fmaf(jB.z, w2, accB[o]);
        accB[o] = fmaf(jB.w, w3, accB[o]);
      }
    }
  }

  const bool mA = (uA >= 0) && (uA < U);
  const bool mB = (uB < U);

  __syncthreads();   // streams dead; reuse as cbf[64][130]
#pragma unroll
  for (int o = 0; o < 16; o++) {
    cbf[(og + o) * CBSTR + lane]      = mA ? accA[o] : -INFINITY;
    cbf[(og + o) * CBSTR + 64 + lane] = mB ? accB[o] : -INFINITY;
  }
  __syncthreads();

  if (lane < VT) {
    int v = v0 + lane;
    if (v < V) {
      const long ybase = ((long)(b * 64 + og)) * V + v;
#pragma unroll
      for (int o = 0; o < 16; o++) {
        const float* cr = cbf + (og + o) * CBSTR + 2 * lane;
        float m = fmaxf(fmaxf(cr[0], cr[1]), cr[2]);
        float e = (m > 0.f) ? m : (expf(m) - 1.f);
        y1[ybase + (long)o * V] = expf(-0.5f * e * e);
      }
    }
  }
}

// ---- batchnorm stats: weighted sequential sum (equiv to dpad gather) ----
// weight(v) = 2-(v&1) for v<mid ; 2 at v==mid ; 1 for v>mid
__global__ __launch_bounds__(256) void bn_partial(const float* __restrict__ y1,
                                                  double* __restrict__ part,
                                                  int V, int mid) {
  const int c = blockIdx.x, chunk = blockIdx.y;   // chunk: 8 b's each
  __shared__ double s1[256], s2[256];
  double a = 0, q = 0;
  for (int b = chunk * 8; b < chunk * 8 + 8; b++) {
    const float* row = y1 + ((long)(b * 64 + c)) * V;
    for (int v = threadIdx.x; v < V; v += 256) {
      float val = row[v];
      float w = (v < mid) ? (float)(2 - (v & 1)) : ((v == mid) ? 2.f : 1.f);
      float wv = w * val;
      a += wv; q += (double)wv * (double)val;
    }
  }
  s1[threadIdx.x] = a; s2[threadIdx.x] = q;
  __syncthreads();
  for (int s = 128; s > 0; s >>= 1) {
    if (threadIdx.x < s) { s1[threadIdx.x] += s1[threadIdx.x + s]; s2[threadIdx.x] += s2[threadIdx.x + s]; }
    __syncthreads();
  }
  if (threadIdx.x == 0) {
    part[(c * 8 + chunk) * 2]     = s1[0];
    part[(c * 8 + chunk) * 2 + 1] = s2[0];
  }
}

// ---- bn final -> affine coefficients: z = A*y + B ----
__global__ __launch_bounds__(128) void bn_final(const double* __restrict__ p0,
                                                const double* __restrict__ p1,
                                                const float* __restrict__ gamma,
                                                const float* __restrict__ beta,
                                                float* __restrict__ cf0,
                                                float* __restrict__ cf1) {
  int t = threadIdx.x;
  const double* pp = (t < 64) ? p0 : p1;
  int c = t & 63;
  double n = (t < 64) ? (double)BB * P0v : (double)BB * P1v;
  double a = 0, q = 0;
  for (int j = 0; j < 8; j++) { a += pp[(c * 8 + j) * 2]; q += pp[(c * 8 + j) * 2 + 1]; }
  double mu = a / n;
  double var = q / n - mu * mu;
  float rsig = 1.0f / sqrtf((float)var + 1e-5f);
  float A = gamma[c] * rsig;
  float Bv = beta[c] - (float)mu * A;
  float* cf = (t < 64) ? cf0 : cf1;
  cf[2 * c] = A;
  cf[2 * c + 1] = Bv;
}

// ---- fused finalize + sew-up gather: branchless via code table ----
__global__ __launch_bounds__(256) void final_fused(
    const float* __restrict__ xtr, const float* __restrict__ y10,
    const float* __restrict__ y11, const float* __restrict__ cf0,
    const float* __restrict__ cf1, const int* __restrict__ codes,
    float* __restrict__ out) {
  const int bc = blockIdx.y;
  const int k = blockIdx.x * 256 + threadIdx.x;
  const int c = bc & 63;
  const float A0 = cf0[2 * c], B0 = cf0[2 * c + 1];
  const float A1 = cf1[2 * c], B1 = cf1[2 * c + 1];
  const float* xr  = xtr + (long)bc * TT;
  const float* y0r = y10 + (long)bc * V0v;
  const float* y1r = y11 + (long)bc * V1v;

  int code = codes[k];
  int type = code & 3;
  int xi = (code >> 2) & 4095;
  int yi = code >> 14;
  float xv = xr[xi];
  const float* yrow = (type == 2) ? y1r : y0r;
  float yv = yrow[yi];
  float A = (type == 0) ? 0.f : ((type == 2) ? A1 : A0);
  float Bv = (type == 0) ? 0.f : ((type == 2) ? B1 : B0);
  float z = fmaf(A, yv, Bv);
  float e = (z > 0.f) ? z : (expf(z) - 1.f);
  out[(long)bc * OUTL + k] = xv + e;
}

extern "C" void kernel_launch(void* const* d_in, const int* in_sizes, int n_in,
                              void* d_out, int out_size, void* d_ws, size_t ws_size,
                              hipStream_t stream) {
  const float* x   = (const float*)d_in[0];
  const float* cv  = (const float*)d_in[1];
  const float* cg  = (const float*)d_in[2];
  const float* cb  = (const float*)d_in[3];
  const float* gam = (const float*)d_in[4];
  const float* bet = (const float*)d_in[5];
  float* out = (float*)d_out;

  char* ws = (char*)d_ws;
  size_t cur = 0;
  auto alloc = [&](size_t bytes) -> char* {
    char* p = ws + cur;
    cur = (cur + bytes + 255) & ~(size_t)255;
    return p;
  };
  double* part   = (double*)alloc(4096 * 2 * sizeof(double));
  double* stats  = (double*)alloc(4 * sizeof(double));
  float*  wt     = (float*)alloc(3 * 64 * 64 * sizeof(float));
  double* bnpt0  = (double*)alloc(64 * 8 * 2 * sizeof(double));
  double* bnpt1  = (double*)alloc(64 * 8 * 2 * sizeof(double));
  float*  cf0    = (float*)alloc(128 * sizeof(float));
  float*  cf1    = (float*)alloc(128 * sizeof(float));
  int*    codes  = (int*)alloc(OUTL * sizeof(int));
  float*  xtr    = (float*)alloc((size_t)BB * CC * TT * sizeof(float));
  float*  y10    = (float*)alloc((size_t)4096 * V0v * sizeof(float));
  float*  y11    = (float*)alloc((size_t)4096 * V1v * sizeof(float));

  transpose_stats<<<dim3(64, 64), 256, 0, stream>>>(x, xtr, part);
  prep<<<89, 256, 0, stream>>>(part, stats, cv, cg, wt, codes);

  conv_pool<<<dim3(64, (V0v + VT - 1) / VT), 256, 0, stream>>>(
      x, wt, cb, stats, y10, L0v, U0v, V0v, 2, 1);
  conv_pool<<<dim3(64, (V1v + VT - 1) / VT), 256, 0, stream>>>(
      x, wt, cb, stats, y11, L1v, U1v, V1v, 4, 3);

  bn_partial<<<dim3(64, 8), 256, 0, stream>>>(y10, bnpt0, V0v, 1024);
  bn_partial<<<dim3(64, 8), 256, 0, stream>>>(y11, bnpt1, V1v, 512);
  bn_final<<<1, 128, 0, stream>>>(bnpt0, bnpt1, gam, bet, cf0, cf1);

  final_fused<<<dim3(24, 4096), 256, 0, stream>>>(xtr, y10, y11, cf0, cf1, codes, out);
}

// Round 2
// 367.446 us; speedup vs baseline: 1.0810x; 1.0699x over previous
//
#include <hip/hip_runtime.h>
#include <math.h>

#define BB 64
#define TT 4096
#define CC 64

constexpr int L0v = 2048, U0v = 3069, V0v = 1535, P0v = 2048;
constexpr int L1v = 1024, U1v = 1533, V1v = 767,  P1v = 1024;
constexpr int OUTL = 6144;
constexpr long NTOT = (long)BB * TT * CC;
#define VT 31        // pool outputs per block (64 conv outputs, 1 slot/lane)
#define JROWS 46     // max staged t-rows for 64-u range
#define RSTR 47      // odd stride (words) for [c][t] LDS layout -> conflict-free
#define CBSTR 66
#define NB0 50       // ceil(V0v/VT)
#define NB1 25       // ceil(V1v/VT)

// ---- transpose x[b][t][c] -> xtr[b][c][t], fused global sum/sumsq ----
__global__ __launch_bounds__(256) void transpose_stats(const float* __restrict__ x,
                                                       float* __restrict__ xtr,
                                                       double* __restrict__ part) {
  __shared__ float tile[64][65];
  __shared__ double sd1[256], sd2[256];
  const int tt = blockIdx.x;
  const int b = blockIdx.y;
  const int t0 = tt * 64;
  const long xbase = (long)b * TT * CC + (long)t0 * CC;
  const int tid = threadIdx.x;
  double a = 0, q = 0;
  {
    int c = tid & 63;
    for (int r = tid >> 6; r < 64; r += 4) {
      float v = x[xbase + r * 64 + c];
      tile[r][c] = v;
      a += v; q += (double)v * (double)v;
    }
  }
  sd1[tid] = a; sd2[tid] = q;
  __syncthreads();
  {
    int tl = tid & 63;
    for (int cc = tid >> 6; cc < 64; cc += 4)
      xtr[((long)(b * 64 + cc)) * TT + t0 + tl] = tile[tl][cc];
  }
  for (int s = 128; s > 0; s >>= 1) {
    if (tid < s) { sd1[tid] += sd1[tid + s]; sd2[tid] += sd2[tid + s]; }
    __syncthreads();
  }
  if (tid == 0) {
    part[(b * 64 + tt) * 2] = sd1[0];
    part[(b * 64 + tt) * 2 + 1] = sd2[0];
  }
}

// ---------------- closed-form index helpers ----------------
__device__ __host__ inline int pad_idx(int p, int brk, int dup, int sub) {
  if (p < brk) { int q = p / 3; int r = p - 3 * q; return 2 * q + (r == 2 ? 1 : 0); }
  if (p < brk + 2) return dup;
  return p - sub;
}

__device__ inline int fmap_code(int k) {
  if (k == 0) return 2048 + 0;
  if (k == 1) return 0;
  if (k < 5462) {
    int m = k - 2;
    int c = m / 12;
    int j = m - 12 * c;
    if (j <= 3)  return 2048 + (1 + 9 * c + j);
    if (j == 4)  return 1 + 3 * c;
    if (j <= 8)  return 2048 + (9 * c + j);
    if (j == 9)  return 2 + 3 * c;
    if (j == 10) return 2048 + (9 + 9 * c);
    return 3 + 3 * c;
  }
  return k - 4096;
}

// ---- merged prep: block 0 = stats_final, 1..64 = weight_norm, 65..88 = codes ----
__global__ __launch_bounds__(256) void prep(const double* __restrict__ part,
                                            double* __restrict__ stats,
                                            const float* __restrict__ v,
                                            const float* __restrict__ g,
                                            float* __restrict__ wt,
                                            int* __restrict__ codes) {
  const int blk = blockIdx.x;
  const int tid = threadIdx.x;
  if (blk == 0) {
    __shared__ double s1[256], s2[256];
    double a = 0, q = 0;
    for (int i = tid; i < 4096; i += 256) { a += part[2 * i]; q += part[2 * i + 1]; }
    s1[tid] = a; s2[tid] = q;
    __syncthreads();
    for (int s = 128; s > 0; s >>= 1) {
      if (tid < s) { s1[tid] += s1[tid + s]; s2[tid] += s2[tid + s]; }
      __syncthreads();
    }
    if (tid == 0) {
      double n = (double)NTOT;
      double mean = s1[0] / n;
      double var = (s2[0] - s1[0] * s1[0] / n) / (n - 1.0);
      stats[0] = mean; stats[1] = sqrt(var);
      stats[2] = 0.8 / mean;
      stats[3] = 0.8 / sqrt(var);
    }
  } else if (blk <= 64) {
    int o = blk - 1;
    __shared__ float red[256];
    __shared__ float scale;
    float vv = (tid < 192) ? v[o * 192 + tid] : 0.f;
    red[tid] = vv * vv;
    __syncthreads();
    for (int s = 128; s > 0; s >>= 1) {
      if (tid < s) red[tid] += red[tid + s];
      __syncthreads();
    }
    if (tid == 0) scale = g[o] / sqrtf(red[0]);
    __syncthreads();
    if (tid < 192) {
      int i = tid / 3, k = tid - 3 * i;
      wt[(k * 64 + i) * 64 + o] = scale * vv;
    }
  } else {
    int k = (blk - 65) * 256 + tid;
    if (k < OUTL) {
      int s = fmap_code(k);
      int type, xi, yi = 0;
      if (s < 2048) {
        if ((s & 1) == 0) { type = 0; xi = 2 * s; }
        else { int p = s >> 1; yi = pad_idx(p, 768, 512, 257); xi = 4 * p + 3; type = 2; }
      } else {
        int p = s - 2048;
        if ((p & 1) == 0) { type = 0; xi = p; }
        else { int q = p >> 1; yi = pad_idx(q, 1536, 1024, 513); xi = 2 * q + 1; type = 1; }
      }
      codes[k] = type | (xi << 2) | (yi << 14);
    }
  }
}

// ---- bf16 round-to-nearest (tie fix via lsb) ----
__device__ inline unsigned bf16rn(float f) {
  unsigned u = __float_as_uint(f);
  return (u + 0x7fffu + ((u >> 16) & 1u)) >> 16;
}

// ---- fused conv (stride2, dil3) + bias + maxpool(3,s2,p1) + elu + gauss ----
// Both levels in one launch (blockIdx.y < NB0 -> level 0).  LDS layout is
// TRANSPOSED [c][t] with odd stride 47: per ds_read, c is wave-uniform and
// lanes differ only in t (~43 consecutive values) -> <=2-way bank access
// (free), vs ~5-way structural conflicts of the [t][c] layout.  1 u-slot
// per lane (VT=31), LDS 18 KB -> 8 blocks/CU = 32 waves/CU.
__global__ __launch_bounds__(256, 8) void conv_pool(
    const float* __restrict__ x, const float* __restrict__ wt,
    const float* __restrict__ cbias, const double* __restrict__ stats,
    float* __restrict__ y10, float* __restrict__ y11) {
  const int b = blockIdx.x;
  const int yb = blockIdx.y;
  const bool lev0 = yb < NB0;
  const int v0 = (lev0 ? yb : yb - NB0) * VT;
  const int L = lev0 ? L0v : L1v;
  const int U = lev0 ? U0v : U1v;
  const int V = lev0 ? V0v : V1v;
  const int mult = lev0 ? 2 : 4;
  const int off1 = lev0 ? 1 : 3;
  float* __restrict__ y1 = lev0 ? y10 : y11;

  const int tid = threadIdx.x;
  const int lane = tid & 63;
  const int og = __builtin_amdgcn_readfirstlane((tid >> 6) * 16);

  const int u0 = 2 * v0 - 1;
  const int uv_lo = max(u0, 0);
  const int uv_hi = min(u0 + 63, U - 1);
  const int t_lo = (2 * uv_lo) / 3;
  int t_hi = (2 * uv_hi + 6) / 3;
  if (t_hi > L - 1) t_hi = L - 1;
  const int rows = t_hi - t_lo + 1;     // <= 45

  // X1 (fp32, [64][RSTR]) : 12032 B ; X0 (bf16-pairs, [32][RSTR]) : 6016 B
  // total 18048 B ; epilogue cbf[64][66]*4 = 16896 B reuses the region
  __shared__ __align__(16) unsigned char smem8[64 * RSTR * 4 + 32 * RSTR * 4];
  float* X1 = (float*)smem8;
  unsigned int* X0 = (unsigned int*)(smem8 + 64 * RSTR * 4);
  float* cbf = (float*)smem8;

  const float inv_mean = (float)stats[2];
  const float inv_std  = (float)stats[3];
  const long xbase = (long)b * TT * CC;

  // stage the two raw streams, transposed to [c][t]
  for (int idx = tid; idx < rows * 16; idx += 256) {
    int tr = idx >> 4, c4 = (idx & 15) * 4;
    int t = t_lo + tr;
    float4 x0 = *(const float4*)&x[xbase + (long)(mult * t) * CC + c4];
    float4 x1 = *(const float4*)&x[xbase + (long)(mult * t + off1) * CC + c4];
    X1[(c4 + 0) * RSTR + tr] = x1.x;
    X1[(c4 + 1) * RSTR + tr] = x1.y;
    X1[(c4 + 2) * RSTR + tr] = x1.z;
    X1[(c4 + 3) * RSTR + tr] = x1.w;
    X0[((c4 >> 1) + 0) * RSTR + tr] = bf16rn(x0.x) | (bf16rn(x0.y) << 16);
    X0[((c4 >> 1) + 1) * RSTR + tr] = bf16rn(x0.z) | (bf16rn(x0.w) << 16);
  }
  __syncthreads();

  const int uA = u0 + lane;
  const int ucA = min(max(uA, 0), U - 1);
  const int t0A = (2 * ucA) / 3;
  const int rA = 2 * ucA - 3 * t0A;

  const float aA = (rA == 0) ? inv_mean : ((rA == 2) ? inv_std : 0.f);
  const float bA = (rA == 1) ? 1.f : 0.2f;
  const int base = t0A - t_lo;

  float acc[16];
  {
    const float* cb_s = cbias + og;
#pragma unroll
    for (int o = 0; o < 16; o++) acc[o] = cb_s[o];
  }

  for (int k = 0; k < 3; k++) {
    const float* X1k = X1 + base + k;          // col offsets via immediates
    const unsigned int* X0k = X0 + base + k;
    const float* wk = wt + k * 4096 + og;
#pragma unroll 4
    for (int i4 = 0; i4 < 16; i4++) {
      float x1a = X1k[(4 * i4 + 0) * RSTR];
      float x1b = X1k[(4 * i4 + 1) * RSTR];
      float x1c = X1k[(4 * i4 + 2) * RSTR];
      float x1d = X1k[(4 * i4 + 3) * RSTR];
      unsigned int q0 = X0k[(2 * i4 + 0) * RSTR];
      unsigned int q1 = X0k[(2 * i4 + 1) * RSTR];
      float4 j;
      j.x = fmaf(aA, x1a, bA * __uint_as_float(q0 << 16));
      j.y = fmaf(aA, x1b, bA * __uint_as_float(q0 & 0xffff0000u));
      j.z = fmaf(aA, x1c, bA * __uint_as_float(q1 << 16));
      j.w = fmaf(aA, x1d, bA * __uint_as_float(q1 & 0xffff0000u));
      const float* wp = wk + i4 * 256;
#pragma unroll
      for (int o = 0; o < 16; o++) {
        float w0 = wp[o], w1 = wp[64 + o], w2 = wp[128 + o], w3 = wp[192 + o];
        acc[o] = fmaf(j.x, w0, acc[o]);
        acc[o] = fmaf(j.y, w1, acc[o]);
        acc[o] = fmaf(j.z, w2, acc[o]);
        acc[o] = fmaf(j.w, w3, acc[o]);
      }
    }
  }

  const bool mA = (uA >= 0) && (uA < U);

  __syncthreads();   // streams dead; reuse as cbf[64][66]
#pragma unroll
  for (int o = 0; o < 16; o++)
    cbf[(og + o) * CBSTR + lane] = mA ? acc[o] : -INFINITY;
  __syncthreads();

  if (lane < VT) {
    int v = v0 + lane;
    if (v < V) {
      const long ybase = ((long)(b * 64 + og)) * V + v;
#pragma unroll
      for (int o = 0; o < 16; o++) {
        const float* cr = cbf + (og + o) * CBSTR + 2 * lane;
        float m = fmaxf(fmaxf(cr[0], cr[1]), cr[2]);
        float e = (m > 0.f) ? m : (expf(m) - 1.f);
        y1[ybase + (long)o * V] = expf(-0.5f * e * e);
      }
    }
  }
}

// ---- batchnorm stats, both levels in one launch ----
// weight(v) = 2-(v&1) for v<mid ; 2 at v==mid ; 1 for v>mid
__global__ __launch_bounds__(256) void bn_partial(const float* __restrict__ y10,
                                                  const float* __restrict__ y11,
                                                  double* __restrict__ p0,
                                                  double* __restrict__ p1) {
  const int c = blockIdx.x, ch = blockIdx.y;   // ch 0..15
  const bool lev0 = ch < 8;
  const int chunk = ch & 7;
  const float* y1 = lev0 ? y10 : y11;
  double* part = lev0 ? p0 : p1;
  const int V = lev0 ? V0v : V1v;
  const int mid = lev0 ? 1024 : 512;
  __shared__ double s1[256], s2[256];
  double a = 0, q = 0;
  for (int b = chunk * 8; b < chunk * 8 + 8; b++) {
    const float* row = y1 + ((long)(b * 64 + c)) * V;
    for (int v = threadIdx.x; v < V; v += 256) {
      float val = row[v];
      float w = (v < mid) ? (float)(2 - (v & 1)) : ((v == mid) ? 2.f : 1.f);
      float wv = w * val;
      a += wv; q += (double)wv * (double)val;
    }
  }
  s1[threadIdx.x] = a; s2[threadIdx.x] = q;
  __syncthreads();
  for (int s = 128; s > 0; s >>= 1) {
    if (threadIdx.x < s) { s1[threadIdx.x] += s1[threadIdx.x + s]; s2[threadIdx.x] += s2[threadIdx.x + s]; }
    __syncthreads();
  }
  if (threadIdx.x == 0) {
    part[(c * 8 + chunk) * 2]     = s1[0];
    part[(c * 8 + chunk) * 2 + 1] = s2[0];
  }
}

// ---- bn final -> affine coefficients: z = A*y + B ----
__global__ __launch_bounds__(128) void bn_final(const double* __restrict__ p0,
                                                const double* __restrict__ p1,
                                                const float* __restrict__ gamma,
                                                const float* __restrict__ beta,
                                                float* __restrict__ cf0,
                                                float* __restrict__ cf1) {
  int t = threadIdx.x;
  const double* pp = (t < 64) ? p0 : p1;
  int c = t & 63;
  double n = (t < 64) ? (double)BB * P0v : (double)BB * P1v;
  double a = 0, q = 0;
  for (int j = 0; j < 8; j++) { a += pp[(c * 8 + j) * 2]; q += pp[(c * 8 + j) * 2 + 1]; }
  double mu = a / n;
  double var = q / n - mu * mu;
  float rsig = 1.0f / sqrtf((float)var + 1e-5f);
  float A = gamma[c] * rsig;
  float Bv = beta[c] - (float)mu * A;
  float* cf = (t < 64) ? cf0 : cf1;
  cf[2 * c] = A;
  cf[2 * c + 1] = Bv;
}

// ---- fused finalize + sew-up gather: branchless via code table ----
__global__ __launch_bounds__(256) void final_fused(
    const float* __restrict__ xtr, const float* __restrict__ y10,
    const float* __restrict__ y11, const float* __restrict__ cf0,
    const float* __restrict__ cf1, const int* __restrict__ codes,
    float* __restrict__ out) {
  const int bc = blockIdx.y;
  const int k = blockIdx.x * 256 + threadIdx.x;
  const int c = bc & 63;
  const float A0 = cf0[2 * c], B0 = cf0[2 * c + 1];
  const float A1 = cf1[2 * c], B1 = cf1[2 * c + 1];
  const float* xr  = xtr + (long)bc * TT;
  const float* y0r = y10 + (long)bc * V0v;
  const float* y1r = y11 + (long)bc * V1v;

  int code = codes[k];
  int type = code & 3;
  int xi = (code >> 2) & 4095;
  int yi = code >> 14;
  float xv = xr[xi];
  const float* yrow = (type == 2) ? y1r : y0r;
  float yv = yrow[yi];
  float A = (type == 0) ? 0.f : ((type == 2) ? A1 : A0);
  float Bv = (type == 0) ? 0.f : ((type == 2) ? B1 : B0);
  float z = fmaf(A, yv, Bv);
  float e = (z > 0.f) ? z : (expf(z) - 1.f);
  out[(long)bc * OUTL + k] = xv + e;
}

extern "C" void kernel_launch(void* const* d_in, const int* in_sizes, int n_in,
                              void* d_out, int out_size, void* d_ws, size_t ws_size,
                              hipStream_t stream) {
  const float* x   = (const float*)d_in[0];
  const float* cv  = (const float*)d_in[1];
  const float* cg  = (const float*)d_in[2];
  const float* cb  = (const float*)d_in[3];
  const float* gam = (const float*)d_in[4];
  const float* bet = (const float*)d_in[5];
  float* out = (float*)d_out;

  char* ws = (char*)d_ws;
  size_t cur = 0;
  auto alloc = [&](size_t bytes) -> char* {
    char* p = ws + cur;
    cur = (cur + bytes + 255) & ~(size_t)255;
    return p;
  };
  double* part   = (double*)alloc(4096 * 2 * sizeof(double));
  double* stats  = (double*)alloc(4 * sizeof(double));
  float*  wt     = (float*)alloc(3 * 64 * 64 * sizeof(float));
  double* bnpt0  = (double*)alloc(64 * 8 * 2 * sizeof(double));
  double* bnpt1  = (double*)alloc(64 * 8 * 2 * sizeof(double));
  float*  cf0    = (float*)alloc(128 * sizeof(float));
  float*  cf1    = (float*)alloc(128 * sizeof(float));
  int*    codes  = (int*)alloc(OUTL * sizeof(int));
  float*  xtr    = (float*)alloc((size_t)BB * CC * TT * sizeof(float));
  float*  y10    = (float*)alloc((size_t)4096 * V0v * sizeof(float));
  float*  y11    = (float*)alloc((size_t)4096 * V1v * sizeof(float));

  transpose_stats<<<dim3(64, 64), 256, 0, stream>>>(x, xtr, part);
  prep<<<89, 256, 0, stream>>>(part, stats, cv, cg, wt, codes);

  conv_pool<<<dim3(64, NB0 + NB1), 256, 0, stream>>>(x, wt, cb, stats, y10, y11);

  bn_partial<<<dim3(64, 16), 256, 0, stream>>>(y10, y11, bnpt0, bnpt1);
  bn_final<<<1, 128, 0, stream>>>(bnpt0, bnpt1, gam, bet, cf0, cf1);

  final_fused<<<dim3(24, 4096), 256, 0, stream>>>(xtr, y10, y11, cf0, cf1, codes, out);
}